// Round 5
// baseline (346.523 us; speedup 1.0000x reference)
//
#include <hip/hip_runtime.h>
#include <math.h>

#define BB 256
#define LL 500
#define EE 300
#define NROWS (BB * LL)      // 128000
#define NDP 20               // padded dot vectors (18 real + 2 zero)
#define NDW 5                // dot vectors per wave (4 waves x 5 = 20)
#define KT 32                // k per tile
#define NT 10                // tiles (320 = 10*32, k 300..319 zero-padded)
#define KPAD (NT * KT)       // 320
#define WR 64                // dot rows per block (= 58 outputs + 6 halo)
#define OPW 58               // outputs per block
#define JPB 9                // blocks per batch (9*58 = 522 >= 500)
#define XSTR 33              // x LDS row stride (odd -> 2-way banks = free)
#define DSTR 21              // dots LDS row stride (odd)

// ---------------------------------------------------------------------------
// R11: d-split + block-shared x. R10's counters isolated the stall: grid 576
// blocks = 2.25 waves/SIMD (Occupancy 23%), and per k-tile each wave pulled
// 288 uniform weight floats through SMEM -- too big for the ~102-SGPR file,
// forcing serial issue/wait/use sub-chunks in the same lgkmcnt as the x
// ds_reads => ~14.6k cyc/tile for ~600 cyc of FMA, nothing to hide it.
// Fix: the 4 waves of a block split the 20 (padded) dot vectors 5-each, so
// (a) per-wave weight chunk is 40 floats -> fits SGPRs, pipelines, and
// (b) all waves consume the SAME 64 x-rows -> x staged once per BLOCK
// (16.9 KB dbuf) -> job = block -> grid 2304 = 9 blocks/CU, 7 resident by
// LDS (22.3 KB) = 7 waves/SIMD (3.1x R10) to hide SMEM/LDS/HBM latency.
// Kept from R10: lane=row (no cross-lane reduce), SGPR weights via d-major
// wt[] prepass, no spill. Cost: 1 barrier per tile (10), cheap at this
// residency.
// ---------------------------------------------------------------------------

__global__ void wt_transpose(
    const float* __restrict__ aw3, const float* __restrict__ aw5,
    const float* __restrict__ aw7, const float* __restrict__ cw3,
    const float* __restrict__ cw5, const float* __restrict__ cw7,
    float* __restrict__ wt)   // d-major: wt[d][KPAD], 20 x 320
{
    const int idx = blockIdx.x * 256 + threadIdx.x;
    if (idx >= NDP * KPAD) return;
    const int d = idx / KPAD;
    const int k = idx - d * KPAD;
    float v = 0.0f;
    if (k < EE && d < 18) {
        if      (d < 3)  v = aw3[d * EE + k];
        else if (d == 3) v = cw3[k];
        else if (d < 9)  v = aw5[(d - 4) * EE + k];
        else if (d == 9) v = cw5[k];
        else if (d < 17) v = aw7[(d - 10) * EE + k];
        else             v = cw7[k];
    }
    wt[idx] = v;
}

__global__ __launch_bounds__(256) void fused_kernel(
    const float* __restrict__ x, const float* __restrict__ wt,
    const float* __restrict__ ab3, const float* __restrict__ cb3,
    const float* __restrict__ ab5, const float* __restrict__ cb5,
    const float* __restrict__ ab7, const float* __restrict__ cb7,
    float* __restrict__ out)
{
    __shared__ float xlds[2][WR * XSTR];   // 2 x 64 x 33 x 4B = 16.9 KB
    __shared__ float dlds[WR * DSTR];      // 64 x 21 x 4B = 5.4 KB

    const int tid   = threadIdx.x;
    const int wave  = tid >> 6;
    const int lane  = tid & 63;
    const int batch = blockIdx.x / JPB;
    const int t     = blockIdx.x - batch * JPB;    // 0..8
    const int l0    = t * OPW - 3;                 // global l of local row 0

    const float* xbb = x + (size_t)batch * LL * EE;

    // ---- staging geometry: thread t -> row tid>>2, two float4 chunks ----
    const int srow = tid >> 2;                     // 0..63
    const int sc0  = (tid & 3) * 2;                // f4 chunk within tile: sc0, sc0+1
    const float4* srp;
    {
        int gl = l0 + srow;
        gl = gl < 0 ? 0 : (gl >= LL ? LL - 1 : gl);
        srp = (const float4*)(xbb + (size_t)gl * EE);
    }

    float4 g0, g1;
#define STAGE_LOAD(k0)                                                      \
    {                                                                       \
        const int f0 = (k0) / 4 + sc0;                                      \
        g0 = (f0 < 75)     ? srp[f0]     : float4{0.f, 0.f, 0.f, 0.f};      \
        g1 = (f0 + 1 < 75) ? srp[f0 + 1] : float4{0.f, 0.f, 0.f, 0.f};      \
    }
#define STAGE_WRITE(buf)                                                    \
    {                                                                       \
        float* dst = &xlds[buf][srow * XSTR + sc0 * 4];                     \
        dst[0] = g0.x; dst[1] = g0.y; dst[2] = g0.z; dst[3] = g0.w;         \
        dst[4] = g1.x; dst[5] = g1.y; dst[6] = g1.z; dst[7] = g1.w;         \
    }

    // prologue: tile 0 -> buffer 0
    STAGE_LOAD(0)
    STAGE_WRITE(0)
    __syncthreads();

    // this wave's 5 weight rows (d-major, uniform address -> s_load)
    const float* wd = wt + (size_t)(wave * NDW) * KPAD;

    float acc[NDW];
#pragma unroll
    for (int d = 0; d < NDW; ++d) acc[d] = 0.0f;

#pragma unroll 1
    for (int tt = 0; tt < NT; ++tt) {
        // issue next tile's global loads (in flight under this tile's work)
        if (tt + 1 < NT) { STAGE_LOAD((tt + 1) * KT) }

        // compute this tile: 32 private-row ds_reads, 160 FMA w/ SGPR weights
        const float* xb = &xlds[tt & 1][lane * XSTR];
        const float* wk = wd + tt * KT;
#pragma unroll
        for (int kc = 0; kc < KT; ++kc) {
            const float xv = xb[kc];
#pragma unroll
            for (int d = 0; d < NDW; ++d)
                acc[d] = fmaf(wk[d * KPAD + kc], xv, acc[d]);
        }

        // land next tile in the other buffer; barrier publishes it and
        // guarantees everyone is done reading before the following overwrite
        if (tt + 1 < NT) { STAGE_WRITE((tt + 1) & 1) }
        __syncthreads();
    }
#undef STAGE_LOAD
#undef STAGE_WRITE

    // ---- dots -> dlds: wave w writes d-columns w*5..w*5+4 for its lane-row
    {
        const int gr = l0 + lane;
        const float vf = (gr >= 0 && gr < LL) ? 1.0f : 0.0f;
#pragma unroll
        for (int d = 0; d < NDW; ++d)
            dlds[lane * DSTR + wave * NDW + d] = acc[d] * vf;
    }
    __syncthreads();

    // ---- epilogue: wave 0, lane = center row, all 3 branches ----
    if (wave == 0 && lane >= 3 && lane < 3 + OPW) {
        const int lo = l0 + lane;
        if (lo < LL) {
            const int r = batch * LL + lo;
            const float cen3 = dlds[lane * DSTR + 3];
            const float cen5 = dlds[lane * DSTR + 9];
            const float cen7 = dlds[lane * DSTR + 17];
            {
                float pre = 0.0f;
#pragma unroll
                for (int tp = 0; tp < 3; ++tp) pre += dlds[(lane + tp - 1) * DSTR + tp];
                const float s = 1.0f / (1.0f + expf(-(pre + ab3[0])));
                out[r] = tanhf(s * cen3 + cb3[0]);
            }
            {
                float pre = 0.0f;
#pragma unroll
                for (int tp = 0; tp < 5; ++tp) pre += dlds[(lane + tp - 2) * DSTR + 4 + tp];
                const float s = 1.0f / (1.0f + expf(-(pre + ab5[0])));
                out[NROWS + r] = tanhf(s * cen5 + cb5[0]);
            }
            {
                float pre = 0.0f;
#pragma unroll
                for (int tp = 0; tp < 7; ++tp) pre += dlds[(lane + tp - 3) * DSTR + 10 + tp];
                const float s = 1.0f / (1.0f + expf(-(pre + ab7[0])));
                out[2 * NROWS + r] = tanhf(s * cen7 + cb7[0]);
            }
        }
    }
}

extern "C" void kernel_launch(void* const* d_in, const int* in_sizes, int n_in,
                              void* d_out, int out_size, void* d_ws, size_t ws_size,
                              hipStream_t stream) {
    const float* x   = (const float*)d_in[0];
    const float* aw3 = (const float*)d_in[1];
    const float* ab3 = (const float*)d_in[2];
    const float* cw3 = (const float*)d_in[3];
    const float* cb3 = (const float*)d_in[4];
    const float* aw5 = (const float*)d_in[5];
    const float* ab5 = (const float*)d_in[6];
    const float* cw5 = (const float*)d_in[7];
    const float* cb5 = (const float*)d_in[8];
    const float* aw7 = (const float*)d_in[9];
    const float* ab7 = (const float*)d_in[10];
    const float* cw7 = (const float*)d_in[11];
    const float* cb7 = (const float*)d_in[12];

    float* wt  = (float*)d_ws;   // 20 x 320 floats = 25.6 KB in workspace
    float* out = (float*)d_out;  // [out3 | out5 | out7]

    // prepass: d-major zero-padded weight matrix
    wt_transpose<<<(NDP * KPAD + 255) / 256, 256, 0, stream>>>(
        aw3, aw5, aw7, cw3, cw5, cw7, wt);

    // 2304 blocks (256 batches x 9), 9/CU launched, 7/CU resident by LDS
    fused_kernel<<<BB * JPB, 256, 0, stream>>>(
        x, wt, ab3, cb3, ab5, cb5, ab7, cb7, out);
}

// Round 6
// 246.819 us; speedup vs baseline: 1.4040x; 1.4040x over previous
//
#include <hip/hip_runtime.h>
#include <math.h>

#define BB 256
#define LL 500
#define EE 300
#define NROWS (BB * LL)      // 128000
#define NJ 18                // 3 (aw3) + 1 (cw3) + 5 (aw5) + 1 (cw5) + 7 (aw7) + 1 (cw7)
#define NC 75                // float4 chunks per row
#define TOUT 56              // outputs per block
#define NTILE 9              // ceil(500/56)
#define DROWS 64             // dot rows per block = TOUT + 6 halo (+2 spare)

// ---------------------------------------------------------------------------
// R12 = R6/R8 proven mapping + register-famine fix. Cross-round diagnosis:
// R8's waves are 94% stalled (VALUBusy 23% at 3 waves/SIMD) because holding
// xall[5][4] (80 VGPR) + acc (72) exceeds the allocation -> the ~90 weight
// ds_read_b128 per tile can't be buffered ahead and serialize at ~120cy each
// (R9's WRITE_SIZE confirmed live-state spills). R10/R11 remaps just moved
// the serial chain to SMEM/VMEM. Fix HERE: explicit depth-2 x-chunk pipeline
// (load c+1/c+2 during compute of c; max 3 chunk-bufs = 48 VGPR live) frees
// ~30 regs so the compiler pipelines weight ds_reads under the FMAs; lgkm-
// only barriers keep x loads in flight across weight staging. One tile per
// block (no next-job prefetch -- that was the spiller), 2304 blocks.
// ---------------------------------------------------------------------------

__device__ __forceinline__ float red16(float v) {
    // sum across each aligned 16-lane group, VALU-only (no LDS pipe)
    int t;
    t = __builtin_amdgcn_update_dpp(0, __float_as_int(v), 0xB1, 0xF, 0xF, true);  // quad_perm [1,0,3,2]
    v += __int_as_float(t);
    t = __builtin_amdgcn_update_dpp(0, __float_as_int(v), 0x4E, 0xF, 0xF, true);  // quad_perm [2,3,0,1]
    v += __int_as_float(t);
    t = __builtin_amdgcn_update_dpp(0, __float_as_int(v), 0x124, 0xF, 0xF, true); // row_ror:4
    v += __int_as_float(t);
    t = __builtin_amdgcn_update_dpp(0, __float_as_int(v), 0x128, 0xF, 0xF, true); // row_ror:8
    v += __int_as_float(t);
    return v;
}

__device__ __forceinline__ void lds_fence_barrier() {
    // publish own LDS ops, cross the barrier, leave global loads in flight
    asm volatile("s_waitcnt lgkmcnt(0)" ::: "memory");
    __builtin_amdgcn_s_barrier();
    asm volatile("" ::: "memory");
}

__global__ __launch_bounds__(256) void fused_kernel(
    const float* __restrict__ x,
    const float* __restrict__ aw3, const float* __restrict__ ab3,
    const float* __restrict__ cw3, const float* __restrict__ cb3,
    const float* __restrict__ aw5, const float* __restrict__ ab5,
    const float* __restrict__ cw5, const float* __restrict__ cb5,
    const float* __restrict__ aw7, const float* __restrict__ ab7,
    const float* __restrict__ cw7, const float* __restrict__ cb7,
    float* __restrict__ out)
{
    __shared__ float4 wlds[NJ * NC];         // 1350 float4 = 21.6 KB
    __shared__ float dlds[DROWS][NJ + 1];    // stride 19, conflict-free (4.9 KB)

    const int tid = threadIdx.x;

    // ---- weight loads FIRST (oldest in vmcnt queue: the staging ds_writes'
    //      counted vmcnt waits retire these while x loads keep flying) ----
    {
        const float4* s3a = (const float4*)aw3;   // 225
        const float4* s3c = (const float4*)cw3;   // 75
        const float4* s5a = (const float4*)aw5;   // 375
        const float4* s5c = (const float4*)cw5;   // 75
        const float4* s7a = (const float4*)aw7;   // 525
        const float4* s7c = (const float4*)cw7;   // 75
        for (int i = tid; i < 225; i += 256) wlds[i]        = s3a[i];
        for (int i = tid; i < 75;  i += 256) wlds[225 + i]  = s3c[i];
        for (int i = tid; i < 375; i += 256) wlds[300 + i]  = s5a[i];
        for (int i = tid; i < 75;  i += 256) wlds[675 + i]  = s5c[i];
        for (int i = tid; i < 525; i += 256) wlds[750 + i]  = s7a[i];
        for (int i = tid; i < 75;  i += 256) wlds[1275 + i] = s7c[i];
    }

    const int b    = blockIdx.x / NTILE;
    const int t    = blockIdx.x % NTILE;
    const int l0   = t * TOUT - 3;           // global l of local dot-row 0
    const int wave = tid >> 6;               // 0..3
    const int lane = tid & 63;
    const int g    = lane >> 4;              // 0..3
    const int j    = lane & 15;              // 0..15
    const int lr   = wave * 16 + g * 4;      // local dot-row base (0..60)

    // clamped x row pointers + validity (invalid rows -> zeroed at dlds store)
    bool valid[4];
    const float4* xr[4];
#pragma unroll
    for (int rr = 0; rr < 4; ++rr) {
        const int l = l0 + lr + rr;
        valid[rr] = (l >= 0) && (l < LL);
        const int lc = l < 0 ? 0 : (l >= LL ? LL - 1 : l);
        xr[rr] = (const float4*)(x + ((size_t)b * LL + lc) * EE);
    }

    // chunk k -> f4 column: k<4 -> j+16k; k==4 -> j+64 (clamped dup j>=11)
#define LOADC(buf, k)                                                       \
    {                                                                       \
        const int c = ((k) == 4) ? ((j < 11) ? (j + 64) : 74) : (j + 16 * (k)); \
        _Pragma("unroll")                                                   \
        for (int rr = 0; rr < 4; ++rr) buf[rr] = xr[rr][c];                 \
    }

    // ---- depth-2 pipeline prologue: chunks 0 and 1 in flight ----
    float4 xc0[4], xc1[4], xc2[4];
    LOADC(xc0, 0)
    LOADC(xc1, 1)

    // weights visible to all waves; x chunk loads stay in flight (lgkm-only)
    lds_fence_barrier();

    float acc[NJ][4];
#pragma unroll
    for (int d = 0; d < NJ; ++d)
#pragma unroll
        for (int rr = 0; rr < 4; ++rr) acc[d][rr] = 0.0f;

#define COMP(buf, c)                                                                \
    {                                                                               \
        _Pragma("unroll")                                                           \
        for (int d = 0; d < NJ; ++d) {                                              \
            const float4 w = wlds[d * NC + (c)];                                    \
            acc[d][0] = fmaf(buf[0].w, w.w, fmaf(buf[0].z, w.z, fmaf(buf[0].y, w.y, fmaf(buf[0].x, w.x, acc[d][0])))); \
            acc[d][1] = fmaf(buf[1].w, w.w, fmaf(buf[1].z, w.z, fmaf(buf[1].y, w.y, fmaf(buf[1].x, w.x, acc[d][1])))); \
            acc[d][2] = fmaf(buf[2].w, w.w, fmaf(buf[2].z, w.z, fmaf(buf[2].y, w.y, fmaf(buf[2].x, w.x, acc[d][2])))); \
            acc[d][3] = fmaf(buf[3].w, w.w, fmaf(buf[3].z, w.z, fmaf(buf[3].y, w.y, fmaf(buf[3].x, w.x, acc[d][3])))); \
        }                                                                           \
    }

    // ---- interleaved pipeline: compute chunk c while c+1, c+2 in flight ----
    COMP(xc0, j)            // uses chunk 0 (waits its vmcnt; chunk 1 flying)
    LOADC(xc2, 2)           // chunk 2 in flight under chunk-1 compute
    COMP(xc1, j + 16)
    LOADC(xc0, 3)           // reuse dead buf: chunk 3
    COMP(xc2, j + 32)
    LOADC(xc1, 4)           // chunk 4 (lanes j>=11 load clamped col, unused)
    COMP(xc0, j + 48)
    if (j < 11) {
        COMP(xc1, j + 64)
    }
#undef COMP
#undef LOADC

    // ---- VALU-only 16-lane reduction (off the LDS pipe) ----
#pragma unroll
    for (int d = 0; d < NJ; ++d)
#pragma unroll
        for (int rr = 0; rr < 4; ++rr) acc[d][rr] = red16(acc[d][rr]);

    // lane j == rr stores row lr+rr into LDS (zeroed if out-of-range)
#pragma unroll
    for (int rr = 0; rr < 4; ++rr) {
        if (j == rr) {
            const float vf = valid[rr] ? 1.0f : 0.0f;
#pragma unroll
            for (int d = 0; d < NJ; ++d) dlds[lr + rr][d] = acc[d][rr] * vf;
        }
    }

    lds_fence_barrier();

    // ---- epilogue: wave w (0..2) handles branch w, lanes 0..55 ----
    if (wave < 3 && lane < TOUT) {
        const int lo = t * TOUT + lane;
        if (lo < LL) {
            const int c = lane + 3;   // local dot-row of the center
            const int r = b * LL + lo;

            if (wave == 0) {
                float pre = 0.0f;
#pragma unroll
                for (int tp = 0; tp < 3; ++tp) pre += dlds[c + tp - 1][tp];
                const float s = 1.0f / (1.0f + expf(-(pre + ab3[0])));
                out[r] = tanhf(s * dlds[c][3] + cb3[0]);
            } else if (wave == 1) {
                float pre = 0.0f;
#pragma unroll
                for (int tp = 0; tp < 5; ++tp) pre += dlds[c + tp - 2][4 + tp];
                const float s = 1.0f / (1.0f + expf(-(pre + ab5[0])));
                out[NROWS + r] = tanhf(s * dlds[c][9] + cb5[0]);
            } else {
                float pre = 0.0f;
#pragma unroll
                for (int tp = 0; tp < 7; ++tp) pre += dlds[c + tp - 3][10 + tp];
                const float s = 1.0f / (1.0f + expf(-(pre + ab7[0])));
                out[2 * NROWS + r] = tanhf(s * dlds[c][17] + cb7[0]);
            }
        }
    }
}

extern "C" void kernel_launch(void* const* d_in, const int* in_sizes, int n_in,
                              void* d_out, int out_size, void* d_ws, size_t ws_size,
                              hipStream_t stream) {
    const float* x   = (const float*)d_in[0];
    const float* aw3 = (const float*)d_in[1];
    const float* ab3 = (const float*)d_in[2];
    const float* cw3 = (const float*)d_in[3];
    const float* cb3 = (const float*)d_in[4];
    const float* aw5 = (const float*)d_in[5];
    const float* ab5 = (const float*)d_in[6];
    const float* cw5 = (const float*)d_in[7];
    const float* cb5 = (const float*)d_in[8];
    const float* aw7 = (const float*)d_in[9];
    const float* ab7 = (const float*)d_in[10];
    const float* cw7 = (const float*)d_in[11];
    const float* cb7 = (const float*)d_in[12];

    float* out = (float*)d_out;  // [out3 | out5 | out7]

    // 256 batches x 9 l-tiles, one dispatch, no workspace
    fused_kernel<<<BB * NTILE, 256, 0, stream>>>(
        x, aw3, ab3, cw3, cb3, aw5, ab5, cw5, cb5, aw7, ab7, cw7, cb7, out);
}